// Round 4
// baseline (49.017 us; speedup 1.0000x reference)
//
#include <hip/hip_runtime.h>
#include <math.h>

#define BN_EPS 1e-5f

// ---------------- math helpers ----------------
__device__ __forceinline__ float fast_exp2(float a) {
#if __has_builtin(__builtin_amdgcn_exp2f)
    return __builtin_amdgcn_exp2f(a);
#else
    return __expf(a * 0.6931471805599453f);
#endif
}
__device__ __forceinline__ float fast_cosrev(float r) {
#if __has_builtin(__builtin_amdgcn_fractf)
    r = __builtin_amdgcn_fractf(r);
#else
    r = r - floorf(r);
#endif
#if __has_builtin(__builtin_amdgcn_cosf)
    return __builtin_amdgcn_cosf(r);
#else
    return __cosf(r * 6.283185307179586f);
#endif
}
// psi(u) = cos(5u)*exp(-u^2/2)  (validated: absmax 0.016 vs fp64 ref)
__device__ __forceinline__ float psi_hw(float u) {
    const float KM = 0.84932181f;            // sqrt(0.5*log2(e))
    const float KC = 0.7957747154594767f;    // 5/(2*pi)
    const float m = u * KM;
    return fast_cosrev(u * KC) * fast_exp2(-(m * m));
}

// ws word layout: [0]=flag [1]=bar1 [2]=bar2 [3]=pad ; then gsum[O], gsq[O]

// ---------------- k_prep: zero control words + BN accumulators ----------------
__global__ void k_prep(unsigned* __restrict__ ws, int O) {
    const int t = threadIdx.x;
    if (t < 4) ws[t] = 0u;
    float* z = (float*)(ws + 4);
    for (int i = t; i < 2 * O; i += blockDim.x) z[i] = 0.f;
}

// ---------------- fused fast path ----------------
constexpr int G_TPB = 256;
constexpr int G_BT  = 128;
constexpr int G_OT  = 64;
constexpr int G_IC  = 64;
constexpr int G_LDR = 68;   // float stride: 68%32=4 -> with bg-interleave, <=2-way conflicts

__global__ __launch_bounds__(G_TPB)
void fused_kan(const float* __restrict__ x, const float* __restrict__ scale,
               const float* __restrict__ bias, const float* __restrict__ weight,
               const float* __restrict__ gamma, const float* __restrict__ beta,
               float* __restrict__ y, unsigned* __restrict__ ws,
               int B, int I, int O, int nob)
{
    __shared__ __align__(16) float xs[G_BT][G_LDR];   // 34.8 KB
    __shared__ __align__(16) float ww[G_IC][G_LDR];   // 17.4 KB (W^T tile)
    __shared__ float reds[4][G_OT];
    __shared__ float redq[4][G_OT];
    __shared__ float As[G_OT], Cs[G_OT];
    __shared__ unsigned sflag;

    unsigned* flag = ws + 0;
    unsigned* bar1 = ws + 1;
    unsigned* bar2 = ws + 2;
    float* gsum = (float*)(ws + 4);
    float* gsq  = gsum + O;

    const int tid = threadIdx.x;
    const unsigned nblocks = gridDim.x;

    // ---- phase 0: check scale/bias uniform across o (bitwise vs row 0) ----
    {
        const int n4 = (O * I) >> 2;
        const int icols4 = I >> 2;
        const int npb = (n4 + (int)nblocks - 1) / (int)nblocks;
        const uint4* s4 = (const uint4*)scale;
        const uint4* b4 = (const uint4*)bias;
        const int gb = blockIdx.x * npb;
        for (int t = tid; t < npb; t += G_TPB) {
            const int g = gb + t;
            if (g < n4) {
                const int c = g % icols4;
                uint4 a = s4[g], a0 = s4[c];
                uint4 b = b4[g], b0 = b4[c];
                unsigned bad = (a.x^a0.x)|(a.y^a0.y)|(a.z^a0.z)|(a.w^a0.w)
                             | (b.x^b0.x)|(b.y^b0.y)|(b.z^b0.z)|(b.w^b0.w);
                if (bad) atomicOr(flag, 1u);
            }
        }
    }
    __syncthreads();   // drains each wave's outstanding atomics before arrival
    if (tid == 0) {
        __hip_atomic_fetch_add(bar1, 1u, __ATOMIC_ACQ_REL, __HIP_MEMORY_SCOPE_AGENT);
        while (__hip_atomic_load(bar1, __ATOMIC_ACQUIRE, __HIP_MEMORY_SCOPE_AGENT) < nblocks)
            __builtin_amdgcn_s_sleep(2);
        sflag = __hip_atomic_load(flag, __ATOMIC_ACQUIRE, __HIP_MEMORY_SCOPE_AGENT);
    }
    __syncthreads();
    if (sflag != 0u) return;   // not uniform -> fallback kernels do the work

    // ---- phase 1: y = psi(x) * W^T, 128x64 tile, BN partials ----
    const int ob = blockIdx.x % nob;
    const int bb = blockIdx.x / nob;
    const int O0 = ob * G_OT;
    const int B0 = bb * G_BT;
    const int og = tid & 15;     // 4 o's: O0 + og*4 + j
    const int bg = tid >> 4;     // 8 rows: B0 + bg + 16*k  (interleaved: bank-safe)

    const int sc4  = (tid & 15) * 4;   // staging column (constant per thread)
    const int srow = tid >> 4;         // staging row base

    float acc[8][4] = {};

    for (int ic = 0; ic < I; ic += G_IC) {
        __syncthreads();
        // x -> psi staging; row-0 scale/bias hoisted (uniform across o)
        {
            float4 sv = *(const float4*)&scale[ic + sc4];
            float4 bv = *(const float4*)&bias [ic + sc4];
            float4 rv, nv;
            rv.x = __builtin_amdgcn_rcpf(sv.x); rv.y = __builtin_amdgcn_rcpf(sv.y);
            rv.z = __builtin_amdgcn_rcpf(sv.z); rv.w = __builtin_amdgcn_rcpf(sv.w);
            nv.x = -bv.x * rv.x; nv.y = -bv.y * rv.y;
            nv.z = -bv.z * rv.z; nv.w = -bv.w * rv.w;
            #pragma unroll
            for (int it = 0; it < G_BT / 16; ++it) {
                const int row = srow + it * 16;
                float4 xv = *(const float4*)&x[(size_t)(B0 + row) * I + ic + sc4];
                float4 pv;
                pv.x = psi_hw(fmaf(xv.x, rv.x, nv.x));
                pv.y = psi_hw(fmaf(xv.y, rv.y, nv.y));
                pv.z = psi_hw(fmaf(xv.z, rv.z, nv.z));
                pv.w = psi_hw(fmaf(xv.w, rv.w, nv.w));
                *(float4*)&xs[row][sc4] = pv;
            }
        }
        // W^T staging (transpose in regs -> b32 scatter)
        #pragma unroll
        for (int it = 0; it < G_OT / 16; ++it) {
            const int o = srow + it * 16;
            float4 wv = *(const float4*)&weight[(size_t)(O0 + o) * I + ic + sc4];
            ww[sc4 + 0][o] = wv.x;
            ww[sc4 + 1][o] = wv.y;
            ww[sc4 + 2][o] = wv.z;
            ww[sc4 + 3][o] = wv.w;
        }
        __syncthreads();

        #pragma unroll 4
        for (int i = 0; i < G_IC; i += 4) {
            float4 xv[8];
            #pragma unroll
            for (int k = 0; k < 8; ++k)
                xv[k] = *(const float4*)&xs[bg + 16 * k][i];
            float4 wv[4];
            #pragma unroll
            for (int e = 0; e < 4; ++e)
                wv[e] = *(const float4*)&ww[i + e][og * 4];
            #pragma unroll
            for (int k = 0; k < 8; ++k) {
                const float* xp = (const float*)&xv[k];
                #pragma unroll
                for (int e = 0; e < 4; ++e) {
                    const float* wp = (const float*)&wv[e];
                    acc[k][0] = fmaf(xp[e], wp[0], acc[k][0]);
                    acc[k][1] = fmaf(xp[e], wp[1], acc[k][1]);
                    acc[k][2] = fmaf(xp[e], wp[2], acc[k][2]);
                    acc[k][3] = fmaf(xp[e], wp[3], acc[k][3]);
                }
            }
        }
    }

    // ---- BN partials: reduce 4 bg's per wave, then cross-wave via LDS ----
    float s[4], q[4];
    #pragma unroll
    for (int j = 0; j < 4; ++j) {
        s[j] = 0.f; q[j] = 0.f;
        #pragma unroll
        for (int k = 0; k < 8; ++k) { s[j] += acc[k][j]; q[j] += acc[k][j] * acc[k][j]; }
        s[j] += __shfl_xor(s[j], 16); s[j] += __shfl_xor(s[j], 32);
        q[j] += __shfl_xor(q[j], 16); q[j] += __shfl_xor(q[j], 32);
    }
    const int wave = tid >> 6, lane = tid & 63;
    if (lane < 16) {
        #pragma unroll
        for (int j = 0; j < 4; ++j) {
            reds[wave][lane * 4 + j] = s[j];
            redq[wave][lane * 4 + j] = q[j];
        }
    }
    __syncthreads();
    if (tid < G_OT) {
        float ss = reds[0][tid] + reds[1][tid] + reds[2][tid] + reds[3][tid];
        float qq = redq[0][tid] + redq[1][tid] + redq[2][tid] + redq[3][tid];
        atomicAdd(&gsum[O0 + tid], ss);
        atomicAdd(&gsq [O0 + tid], qq);
    }
    __syncthreads();   // wave 0 drains its atomics here

    // ---- grid barrier 2 ----
    if (tid == 0) {
        __hip_atomic_fetch_add(bar2, 1u, __ATOMIC_ACQ_REL, __HIP_MEMORY_SCOPE_AGENT);
        while (__hip_atomic_load(bar2, __ATOMIC_ACQUIRE, __HIP_MEMORY_SCOPE_AGENT) < nblocks)
            __builtin_amdgcn_s_sleep(2);
    }
    __syncthreads();

    // ---- phase 2: BN finalize (per-block, 64 o's) + apply in registers ----
    if (tid < G_OT) {
        const int o = O0 + tid;
        const float invB = 1.0f / (float)B;
        float sv = __hip_atomic_load(&gsum[o], __ATOMIC_RELAXED, __HIP_MEMORY_SCOPE_AGENT);
        float qv = __hip_atomic_load(&gsq[o],  __ATOMIC_RELAXED, __HIP_MEMORY_SCOPE_AGENT);
        const float m = sv * invB;
        const float v = fmaxf(qv * invB - m * m, 0.f);
        const float a = gamma[o] * rsqrtf(v + BN_EPS);
        As[tid] = a;
        Cs[tid] = fmaf(-m, a, beta[o]);
    }
    __syncthreads();
    const float a0 = As[og*4+0], a1 = As[og*4+1], a2 = As[og*4+2], a3 = As[og*4+3];
    const float c0 = Cs[og*4+0], c1 = Cs[og*4+1], c2 = Cs[og*4+2], c3 = Cs[og*4+3];
    #pragma unroll
    for (int k = 0; k < 8; ++k) {
        const int row = bg + 16 * k;
        float4 r;
        r.x = fmaf(acc[k][0], a0, c0);
        r.y = fmaf(acc[k][1], a1, c1);
        r.z = fmaf(acc[k][2], a2, c2);
        r.w = fmaf(acc[k][3], a3, c3);
        *(float4*)&y[(size_t)(B0 + row) * O + O0 + og * 4] = r;
    }
}

// ---------------- general fallback (round-1 proven kernel + guard) ----------------
constexpr int BT  = 128;
constexpr int OT  = 32;
constexpr int IC  = 64;
constexpr int TPB = 512;
constexpr int LDR = IC + 4;

__global__ __launch_bounds__(TPB, 4)
void kan_forward(const float* __restrict__ x, const float* __restrict__ scale,
                 const float* __restrict__ bias, const float* __restrict__ weight,
                 const unsigned* __restrict__ flag, int mode,
                 float* __restrict__ y, float* __restrict__ gsum,
                 float* __restrict__ gsq, int B, int I, int O)
{
    if (mode == 0 && *flag == 0u) return;   // fast path handled it

    __shared__ __align__(16) float xs[BT][LDR];
    __shared__ __align__(16) float pr[OT][LDR];
    __shared__ __align__(16) float pc[OT][LDR];
    __shared__ __align__(16) float pw[OT][LDR];

    const int tid = threadIdx.x;
    const int og  = tid & 15;
    const int bg  = tid >> 4;
    const int O0  = blockIdx.x * OT;
    const int B0  = blockIdx.y * BT;

    const float KM = 0.84932181f;
    const float KC = 0.7957747154594767f;

    float acc[4][2] = {{0.f,0.f},{0.f,0.f},{0.f,0.f},{0.f,0.f}};

    for (int ic = 0; ic < I; ic += IC) {
        __syncthreads();
        for (int r = tid; r < BT * (IC/4); r += TPB) {
            const int row = r >> 4;
            const int c4  = (r & 15) * 4;
            float4 v = *(const float4*)&x[(size_t)(B0+row)*I + ic + c4];
            *(float4*)&xs[row][c4] = v;
        }
        for (int r = tid; r < OT * (IC/4); r += TPB) {
            const int row = r >> 4;
            const int c4  = (r & 15) * 4;
            const size_t g = (size_t)(O0+row)*I + ic + c4;
            float4 sv = *(const float4*)&scale[g];
            float4 bv = *(const float4*)&bias[g];
            float4 wv = *(const float4*)&weight[g];
            float4 rv, cv;
            rv.x = 1.0f/sv.x; rv.y = 1.0f/sv.y; rv.z = 1.0f/sv.z; rv.w = 1.0f/sv.w;
            cv.x = -bv.x*rv.x; cv.y = -bv.y*rv.y; cv.z = -bv.z*rv.z; cv.w = -bv.w*rv.w;
            *(float4*)&pr[row][c4] = rv;
            *(float4*)&pc[row][c4] = cv;
            *(float4*)&pw[row][c4] = wv;
        }
        __syncthreads();

        #pragma unroll 2
        for (int i = 0; i < IC; i += 4) {
            float4 xv[4];
            #pragma unroll
            for (int k = 0; k < 4; ++k)
                xv[k] = *(const float4*)&xs[bg*4+k][i];
            #pragma unroll
            for (int j = 0; j < 2; ++j) {
                const int o = og*2 + j;
                const float4 rv = *(const float4*)&pr[o][i];
                const float4 cv = *(const float4*)&pc[o][i];
                const float4 wv = *(const float4*)&pw[o][i];
                const float* rp = (const float*)&rv;
                const float* cp = (const float*)&cv;
                const float* wp = (const float*)&wv;
                #pragma unroll
                for (int k = 0; k < 4; ++k) {
                    const float* xp = (const float*)&xv[k];
                    #pragma unroll
                    for (int e = 0; e < 4; ++e) {
                        const float u  = fmaf(xp[e], rp[e], cp[e]);
                        const float m  = u * KM;
                        const float ex = fast_exp2(-(m*m));
                        const float cs = fast_cosrev(u * KC);
                        acc[k][j] = fmaf(cs*ex, wp[e], acc[k][j]);
                    }
                }
            }
        }
    }

    #pragma unroll
    for (int k = 0; k < 4; ++k) {
        float2 v = make_float2(acc[k][0], acc[k][1]);
        *(float2*)&y[(size_t)(B0 + bg*4 + k)*O + O0 + og*2] = v;
    }

    float s[2], q[2];
    #pragma unroll
    for (int j = 0; j < 2; ++j) {
        s[j] = acc[0][j]+acc[1][j]+acc[2][j]+acc[3][j];
        q[j] = acc[0][j]*acc[0][j]+acc[1][j]*acc[1][j]
             + acc[2][j]*acc[2][j]+acc[3][j]*acc[3][j];
        s[j] += __shfl_xor(s[j], 16); s[j] += __shfl_xor(s[j], 32);
        q[j] += __shfl_xor(q[j], 16); q[j] += __shfl_xor(q[j], 32);
    }
    __syncthreads();
    float* red = &xs[0][0];
    const int wave = tid >> 6;
    const int lane = tid & 63;
    if (lane < 16) {
        red[      wave*32 + og*2 + 0] = s[0];
        red[      wave*32 + og*2 + 1] = s[1];
        red[256 + wave*32 + og*2 + 0] = q[0];
        red[256 + wave*32 + og*2 + 1] = q[1];
    }
    __syncthreads();
    if (tid < OT) {
        float ss = 0.f, qq = 0.f;
        #pragma unroll
        for (int w = 0; w < TPB/64; ++w) {
            ss += red[      w*32 + tid];
            qq += red[256 + w*32 + tid];
        }
        atomicAdd(&gsum[O0 + tid], ss);
        atomicAdd(&gsq [O0 + tid], qq);
    }
}

// ---------------- fallback BN finalize+apply (fused) ----------------
__global__ __launch_bounds__(256)
void bn_fb(float* __restrict__ y, const unsigned* __restrict__ flag, int mode,
           const float* __restrict__ gsum, const float* __restrict__ gsq,
           const float* __restrict__ gamma, const float* __restrict__ beta,
           int B, int O, int n4)
{
    if (mode == 0 && *flag == 0u) return;
    const int p = blockIdx.x * blockDim.x + threadIdx.x;
    if (p >= n4) return;
    float4 v = ((const float4*)y)[p];
    const int o = (p * 4) % O;
    const float invB = 1.0f / (float)B;
    float4 r;
    {
        float m = gsum[o+0]*invB; float vv = fmaxf(gsq[o+0]*invB - m*m, 0.f);
        float a = gamma[o+0]*rsqrtf(vv+BN_EPS); r.x = fmaf(v.x, a, fmaf(-m, a, beta[o+0]));
    }{
        float m = gsum[o+1]*invB; float vv = fmaxf(gsq[o+1]*invB - m*m, 0.f);
        float a = gamma[o+1]*rsqrtf(vv+BN_EPS); r.y = fmaf(v.y, a, fmaf(-m, a, beta[o+1]));
    }{
        float m = gsum[o+2]*invB; float vv = fmaxf(gsq[o+2]*invB - m*m, 0.f);
        float a = gamma[o+2]*rsqrtf(vv+BN_EPS); r.z = fmaf(v.z, a, fmaf(-m, a, beta[o+2]));
    }{
        float m = gsum[o+3]*invB; float vv = fmaxf(gsq[o+3]*invB - m*m, 0.f);
        float a = gamma[o+3]*rsqrtf(vv+BN_EPS); r.w = fmaf(v.w, a, fmaf(-m, a, beta[o+3]));
    }
    ((float4*)y)[p] = r;
}

// ---------------- launch ----------------
extern "C" void kernel_launch(void* const* d_in, const int* in_sizes, int n_in,
                              void* d_out, int out_size, void* d_ws, size_t ws_size,
                              hipStream_t stream)
{
    const float* x      = (const float*)d_in[0];
    const float* scale  = (const float*)d_in[1];
    const float* bias   = (const float*)d_in[2];
    const float* weight = (const float*)d_in[3];
    const float* gamma  = (const float*)d_in[4];
    const float* beta   = (const float*)d_in[5];
    float* y = (float*)d_out;

    const int O = in_sizes[4];
    const int I = in_sizes[1] / O;
    const int B = in_sizes[0] / I;

    unsigned* ws = (unsigned*)d_ws;
    float* gsum = (float*)(ws + 4);
    float* gsq  = gsum + O;

    k_prep<<<1, 256, 0, stream>>>(ws, O);

    const int nblocks = (B / G_BT) * (O / G_OT);
    const int n4o = (B * O) / 4;
    const bool fast_ok = (B % G_BT == 0) && (O % G_OT == 0) && (I % G_IC == 0)
                      && (B % BT == 0) && (O % OT == 0) && (I % IC == 0)
                      && (nblocks <= 256)
                      && (ws_size >= (4 + 2 * (size_t)O) * sizeof(float));

    if (fast_ok) {
        fused_kan<<<nblocks, G_TPB, 0, stream>>>(x, scale, bias, weight, gamma, beta,
                                                 y, ws, B, I, O, O / G_OT);
        kan_forward<<<dim3(O / OT, B / BT), TPB, 0, stream>>>(
            x, scale, bias, weight, ws, 0, y, gsum, gsq, B, I, O);
        bn_fb<<<(n4o + 255) / 256, 256, 0, stream>>>(
            y, ws, 0, gsum, gsq, gamma, beta, B, O, n4o);
    } else {
        kan_forward<<<dim3(O / OT, B / BT), TPB, 0, stream>>>(
            x, scale, bias, weight, ws, 1, y, gsum, gsq, B, I, O);
        bn_fb<<<(n4o + 255) / 256, 256, 0, stream>>>(
            y, ws, 1, gsum, gsq, gamma, beta, B, O, n4o);
    }
}

// Round 5
// 33.822 us; speedup vs baseline: 1.4493x; 1.4493x over previous
//
#include <hip/hip_runtime.h>
#include <math.h>

#define BN_EPS 1e-5f

// ---------------- math helpers ----------------
__device__ __forceinline__ float fast_exp2(float a) {
#if __has_builtin(__builtin_amdgcn_exp2f)
    return __builtin_amdgcn_exp2f(a);
#else
    return __expf(a * 0.6931471805599453f);
#endif
}
__device__ __forceinline__ float fast_cosrev(float r) {
#if __has_builtin(__builtin_amdgcn_fractf)
    r = __builtin_amdgcn_fractf(r);
#else
    r = r - floorf(r);
#endif
#if __has_builtin(__builtin_amdgcn_cosf)
    return __builtin_amdgcn_cosf(r);
#else
    return __cosf(r * 6.283185307179586f);
#endif
}
// psi(u) = cos(5u)*exp(-u^2/2)   (validated: absmax 0.016 vs ref)
__device__ __forceinline__ float psi_hw(float u) {
    const float KM = 0.84932181f;            // sqrt(0.5*log2(e))
    const float KC = 0.7957747154594767f;    // 5/(2*pi)
    const float m = u * KM;
    return fast_cosrev(u * KC) * fast_exp2(-(m * m));
}

typedef __bf16 bf16x8 __attribute__((ext_vector_type(8)));
typedef float  f32x4  __attribute__((ext_vector_type(4)));

// ws float layout: [0..3]=ctrl(flag@0) | gsumA[O] gsqA[O] gsumB[O] gsqB[O] | A[O] C[O]

// ---------------- uniformity check (flag=1 if any scale/bias row differs from row 0) ----------------
__global__ void k_check(const uint4* __restrict__ scale4, const uint4* __restrict__ bias4,
                        int n4, int icols4, unsigned* __restrict__ flag)
{
    const int g = blockIdx.x * blockDim.x + threadIdx.x;
    if (g >= n4) return;
    const int c = g % icols4;
    uint4 s = scale4[g], s0 = scale4[c];
    uint4 b = bias4[g],  b0 = bias4[c];
    unsigned bad = (s.x ^ s0.x) | (s.y ^ s0.y) | (s.z ^ s0.z) | (s.w ^ s0.w)
                 | (b.x ^ b0.x) | (b.y ^ b0.y) | (b.z ^ b0.z) | (b.w ^ b0.w);
    if (bad) atomicOr(flag, 1u);
}

// ---------------- MFMA fast path: y = psi(x) * W^T (bf16 MFMA), BN partials ----------------
// 64x64 tile / block, 256 threads (4 waves), each wave a 32x32 quadrant.
__global__ __launch_bounds__(256)
void mfma_kan(const float* __restrict__ x, const float* __restrict__ scale,
              const float* __restrict__ bias, const float* __restrict__ weight,
              const unsigned* __restrict__ flag, float* __restrict__ y,
              float* __restrict__ gsum, float* __restrict__ gsq,
              int B, int I, int O, int nob)
{
    if (*flag != 0u) return;   // non-uniform -> fallback kernels handle it

    __shared__ __align__(16) __bf16 Pl[64 * 128];   // psi tile, 16 KB, XOR-swizzled
    __shared__ __align__(16) __bf16 Wl[64 * 128];   // W^T tile, 16 KB, XOR-swizzled
    __shared__ float reds[4][32], redq[4][32];

    const int tid = threadIdx.x;
    const int ob  = blockIdx.x % nob;
    const int bb  = blockIdx.x / nob;
    const int O0  = ob * 64;
    const int B0  = bb * 64;

    const int lane = tid & 63;
    const int w    = tid >> 6;        // wave 0..3
    const int wm   = w >> 1;          // row half
    const int wn   = w & 1;           // col half
    const int m16  = lane & 15;
    const int kg   = lane >> 4;       // k-group 0..3

    const int sr = tid >> 2;          // staging row 0..63
    const int k0 = (tid & 3) << 5;    // staging k-base {0,32,64,96}

    f32x4 acc[2][2] = {};

    for (int ic = 0; ic < I; ic += 128) {
        __syncthreads();
        // ---- stage psi(x) and bf16(W) tiles (swizzled: byte ^= (row&7)<<4) ----
        #pragma unroll
        for (int j = 0; j < 4; ++j) {
            const int kk = k0 + j * 8;
            float4 s0 = *(const float4*)&scale[ic + kk];
            float4 s1 = *(const float4*)&scale[ic + kk + 4];
            float4 b0 = *(const float4*)&bias [ic + kk];
            float4 b1 = *(const float4*)&bias [ic + kk + 4];
            float4 x0 = *(const float4*)&x[(size_t)(B0 + sr) * I + ic + kk];
            float4 x1 = *(const float4*)&x[(size_t)(B0 + sr) * I + ic + kk + 4];
            float4 w0 = *(const float4*)&weight[(size_t)(O0 + sr) * I + ic + kk];
            float4 w1 = *(const float4*)&weight[(size_t)(O0 + sr) * I + ic + kk + 4];
            bf16x8 pv, wv;
            #pragma unroll
            for (int e = 0; e < 4; ++e) {
                const float sa = ((const float*)&s0)[e];
                const float ba = ((const float*)&b0)[e];
                const float xa = ((const float*)&x0)[e];
                const float wa = ((const float*)&w0)[e];
                const float ra = __builtin_amdgcn_rcpf(sa);
                pv[e] = (__bf16)psi_hw((xa - ba) * ra);
                wv[e] = (__bf16)wa;
                const float sb = ((const float*)&s1)[e];
                const float bbv = ((const float*)&b1)[e];
                const float xb = ((const float*)&x1)[e];
                const float wb = ((const float*)&w1)[e];
                const float rb = __builtin_amdgcn_rcpf(sb);
                pv[e + 4] = (__bf16)psi_hw((xb - bbv) * rb);
                wv[e + 4] = (__bf16)wb;
            }
            unsigned byte = (unsigned)(sr * 256 + kk * 2);
            byte ^= (unsigned)((sr & 7) << 4);
            *reinterpret_cast<bf16x8*>(reinterpret_cast<char*>(Pl) + byte) = pv;
            *reinterpret_cast<bf16x8*>(reinterpret_cast<char*>(Wl) + byte) = wv;
        }
        __syncthreads();

        // ---- 4 k-steps of 16x16x32 MFMA per quadrant ----
        #pragma unroll
        for (int ks = 0; ks < 4; ++ks) {
            bf16x8 a[2], b[2];
            #pragma unroll
            for (int mi = 0; mi < 2; ++mi) {
                const int row = wm * 32 + mi * 16 + m16;
                unsigned byte = (unsigned)(row * 256 + ks * 64 + kg * 16);
                byte ^= (unsigned)((row & 7) << 4);
                a[mi] = *reinterpret_cast<const bf16x8*>(reinterpret_cast<const char*>(Pl) + byte);
            }
            #pragma unroll
            for (int ni = 0; ni < 2; ++ni) {
                const int row = wn * 32 + ni * 16 + m16;
                unsigned byte = (unsigned)(row * 256 + ks * 64 + kg * 16);
                byte ^= (unsigned)((row & 7) << 4);
                b[ni] = *reinterpret_cast<const bf16x8*>(reinterpret_cast<const char*>(Wl) + byte);
            }
            #pragma unroll
            for (int mi = 0; mi < 2; ++mi)
                #pragma unroll
                for (int ni = 0; ni < 2; ++ni)
                    acc[mi][ni] = __builtin_amdgcn_mfma_f32_16x16x32_bf16(
                        a[mi], b[ni], acc[mi][ni], 0, 0, 0);
        }
    }

    // ---- y write: C/D layout col=lane&15, row=(lane>>4)*4+reg ----
    #pragma unroll
    for (int mi = 0; mi < 2; ++mi) {
        const int rbase = B0 + wm * 32 + mi * 16 + kg * 4;
        #pragma unroll
        for (int ni = 0; ni < 2; ++ni) {
            const int col = O0 + wn * 32 + ni * 16 + m16;
            #pragma unroll
            for (int r = 0; r < 4; ++r)
                y[(size_t)(rbase + r) * O + col] = acc[mi][ni][r];
        }
    }

    // ---- BN partials: per-col sums over this wave's 32 rows, then cross-wave ----
    float s0 = 0.f, s1 = 0.f, q0 = 0.f, q1 = 0.f;
    #pragma unroll
    for (int mi = 0; mi < 2; ++mi)
        #pragma unroll
        for (int r = 0; r < 4; ++r) {
            const float v0 = acc[mi][0][r], v1 = acc[mi][1][r];
            s0 += v0; q0 += v0 * v0;
            s1 += v1; q1 += v1 * v1;
        }
    s0 += __shfl_xor(s0, 16); s0 += __shfl_xor(s0, 32);
    q0 += __shfl_xor(q0, 16); q0 += __shfl_xor(q0, 32);
    s1 += __shfl_xor(s1, 16); s1 += __shfl_xor(s1, 32);
    q1 += __shfl_xor(q1, 16); q1 += __shfl_xor(q1, 32);
    if (lane < 16) {
        reds[w][m16]      = s0;  redq[w][m16]      = q0;
        reds[w][16 + m16] = s1;  redq[w][16 + m16] = q1;
    }
    __syncthreads();
    if (tid < 64) {
        const int wn2 = tid >> 5;    // col half
        const int cw  = tid & 31;    // col within half
        const float ss = reds[wn2][cw] + reds[2 + wn2][cw];
        const float qq = redq[wn2][cw] + redq[2 + wn2][cw];
        atomicAdd(&gsum[O0 + wn2 * 32 + cw], ss);
        atomicAdd(&gsq [O0 + wn2 * 32 + cw], qq);
    }
}

// ---------------- general fallback (proven round-1 kernel, flag-gated) ----------------
constexpr int BT  = 128;
constexpr int OT  = 32;
constexpr int IC  = 64;
constexpr int TPB = 512;
constexpr int LDR = IC + 4;

__global__ __launch_bounds__(TPB, 4)
void kan_forward(const float* __restrict__ x, const float* __restrict__ scale,
                 const float* __restrict__ bias, const float* __restrict__ weight,
                 const unsigned* __restrict__ flag, int mode,
                 float* __restrict__ y, float* __restrict__ gsum,
                 float* __restrict__ gsq, int B, int I, int O)
{
    if (mode == 0 && *flag == 0u) return;   // fast path handled it

    __shared__ __align__(16) float xs[BT][LDR];
    __shared__ __align__(16) float pr[OT][LDR];
    __shared__ __align__(16) float pc[OT][LDR];
    __shared__ __align__(16) float pw[OT][LDR];

    const int tid = threadIdx.x;
    const int og  = tid & 15;
    const int bg  = tid >> 4;
    const int O0  = blockIdx.x * OT;
    const int B0  = blockIdx.y * BT;

    const float KM = 0.84932181f;
    const float KC = 0.7957747154594767f;

    float acc[4][2] = {{0.f,0.f},{0.f,0.f},{0.f,0.f},{0.f,0.f}};

    for (int ic = 0; ic < I; ic += IC) {
        __syncthreads();
        for (int r = tid; r < BT * (IC/4); r += TPB) {
            const int row = r >> 4;
            const int c4  = (r & 15) * 4;
            float4 v = *(const float4*)&x[(size_t)(B0+row)*I + ic + c4];
            *(float4*)&xs[row][c4] = v;
        }
        for (int r = tid; r < OT * (IC/4); r += TPB) {
            const int row = r >> 4;
            const int c4  = (r & 15) * 4;
            const size_t g = (size_t)(O0+row)*I + ic + c4;
            float4 sv = *(const float4*)&scale[g];
            float4 bv = *(const float4*)&bias[g];
            float4 wv = *(const float4*)&weight[g];
            float4 rv, cv;
            rv.x = 1.0f/sv.x; rv.y = 1.0f/sv.y; rv.z = 1.0f/sv.z; rv.w = 1.0f/sv.w;
            cv.x = -bv.x*rv.x; cv.y = -bv.y*rv.y; cv.z = -bv.z*rv.z; cv.w = -bv.w*rv.w;
            *(float4*)&pr[row][c4] = rv;
            *(float4*)&pc[row][c4] = cv;
            *(float4*)&pw[row][c4] = wv;
        }
        __syncthreads();

        #pragma unroll 2
        for (int i = 0; i < IC; i += 4) {
            float4 xv[4];
            #pragma unroll
            for (int k = 0; k < 4; ++k)
                xv[k] = *(const float4*)&xs[bg*4+k][i];
            #pragma unroll
            for (int j = 0; j < 2; ++j) {
                const int o = og*2 + j;
                const float4 rv = *(const float4*)&pr[o][i];
                const float4 cv = *(const float4*)&pc[o][i];
                const float4 wv = *(const float4*)&pw[o][i];
                const float* rp = (const float*)&rv;
                const float* cp = (const float*)&cv;
                const float* wp = (const float*)&wv;
                #pragma unroll
                for (int k = 0; k < 4; ++k) {
                    const float* xp = (const float*)&xv[k];
                    #pragma unroll
                    for (int e = 0; e < 4; ++e) {
                        const float u  = fmaf(xp[e], rp[e], cp[e]);
                        const float m  = u * KM;
                        const float ex = fast_exp2(-(m*m));
                        const float cs = fast_cosrev(u * KC);
                        acc[k][j] = fmaf(cs*ex, wp[e], acc[k][j]);
                    }
                }
            }
        }
    }

    #pragma unroll
    for (int k = 0; k < 4; ++k) {
        float2 v = make_float2(acc[k][0], acc[k][1]);
        *(float2*)&y[(size_t)(B0 + bg*4 + k)*O + O0 + og*2] = v;
    }

    float s[2], q[2];
    #pragma unroll
    for (int j = 0; j < 2; ++j) {
        s[j] = acc[0][j]+acc[1][j]+acc[2][j]+acc[3][j];
        q[j] = acc[0][j]*acc[0][j]+acc[1][j]*acc[1][j]
             + acc[2][j]*acc[2][j]+acc[3][j]*acc[3][j];
        s[j] += __shfl_xor(s[j], 16); s[j] += __shfl_xor(s[j], 32);
        q[j] += __shfl_xor(q[j], 16); q[j] += __shfl_xor(q[j], 32);
    }
    __syncthreads();
    float* red = &xs[0][0];
    const int wave = tid >> 6;
    const int lane = tid & 63;
    if (lane < 16) {
        red[      wave*32 + og*2 + 0] = s[0];
        red[      wave*32 + og*2 + 1] = s[1];
        red[256 + wave*32 + og*2 + 0] = q[0];
        red[256 + wave*32 + og*2 + 1] = q[1];
    }
    __syncthreads();
    if (tid < OT) {
        float ss = 0.f, qq = 0.f;
        #pragma unroll
        for (int w2 = 0; w2 < TPB/64; ++w2) {
            ss += red[      w2*32 + tid];
            qq += red[256 + w2*32 + tid];
        }
        atomicAdd(&gsum[O0 + tid], ss);
        atomicAdd(&gsq [O0 + tid], qq);
    }
}

// ---------------- BN coefficients (picks fast/fallback accumulator set) ----------------
__global__ void bn_coef(const unsigned* __restrict__ flag,
                        const float* __restrict__ gsA, const float* __restrict__ gqA,
                        const float* __restrict__ gsB, const float* __restrict__ gqB,
                        const float* __restrict__ gamma, const float* __restrict__ beta,
                        float* __restrict__ A, float* __restrict__ C, int B, int O, int useB)
{
    const int o = blockIdx.x * blockDim.x + threadIdx.x;
    if (o >= O) return;
    const bool fb = (useB != 0) || (*flag != 0u);
    const float sv = fb ? gsB[o] : gsA[o];
    const float qv = fb ? gqB[o] : gqA[o];
    const float invB = 1.0f / (float)B;
    const float m = sv * invB;
    const float v = fmaxf(qv * invB - m * m, 0.f);
    const float a = gamma[o] * rsqrtf(v + BN_EPS);
    A[o] = a;
    C[o] = fmaf(-m, a, beta[o]);
}

// ---------------- streaming BN apply (in-place, grid-stride) ----------------
__global__ __launch_bounds__(256)
void bn_apply(float* y, const float* __restrict__ A,
              const float* __restrict__ C, int O, int n4)
{
    const int stride = gridDim.x * blockDim.x;
    for (int p = blockIdx.x * blockDim.x + threadIdx.x; p < n4; p += stride) {
        float4 v = ((const float4*)y)[p];
        const int o = (p * 4) % O;
        const float4 a = *(const float4*)&A[o];
        const float4 c = *(const float4*)&C[o];
        float4 r;
        r.x = fmaf(v.x, a.x, c.x);
        r.y = fmaf(v.y, a.y, c.y);
        r.z = fmaf(v.z, a.z, c.z);
        r.w = fmaf(v.w, a.w, c.w);
        ((float4*)y)[p] = r;
    }
}

// ---------------- launch ----------------
extern "C" void kernel_launch(void* const* d_in, const int* in_sizes, int n_in,
                              void* d_out, int out_size, void* d_ws, size_t ws_size,
                              hipStream_t stream)
{
    const float* x      = (const float*)d_in[0];
    const float* scale  = (const float*)d_in[1];
    const float* bias   = (const float*)d_in[2];
    const float* weight = (const float*)d_in[3];
    const float* gamma  = (const float*)d_in[4];
    const float* beta   = (const float*)d_in[5];
    float* y = (float*)d_out;

    const int O = in_sizes[4];
    const int I = in_sizes[1] / O;
    const int B = in_sizes[0] / I;

    float* wsf = (float*)d_ws;
    unsigned* flag = (unsigned*)d_ws;
    const int n4o = (B * O) / 4;
    const int napply = n4o < 2048 * 256 ? ((n4o + 255) / 256) : 2048;

    const bool fast_ok = (B % 64 == 0) && (O % 64 == 0) && (I % 128 == 0)
                      && (B % BT == 0) && (O % OT == 0) && (I % IC == 0)
                      && (ws_size >= (4 + 6 * (size_t)O) * sizeof(float));

    if (fast_ok) {
        float* gsA = wsf + 4;
        float* gqA = gsA + O;
        float* gsB = gqA + O;
        float* gqB = gsB + O;
        float* A   = gqB + O;
        float* C   = A + O;

        hipMemsetAsync(d_ws, 0, (4 + 4 * (size_t)O) * sizeof(float), stream);

        const int n4 = (O * I) / 4;
        k_check<<<(n4 + 255) / 256, 256, 0, stream>>>(
            (const uint4*)scale, (const uint4*)bias, n4, I / 4, flag);

        const int nob = O / 64;
        mfma_kan<<<(B / 64) * nob, 256, 0, stream>>>(
            x, scale, bias, weight, flag, y, gsA, gqA, B, I, O, nob);

        kan_forward<<<dim3(O / OT, B / BT), TPB, 0, stream>>>(
            x, scale, bias, weight, flag, 0, y, gsB, gqB, B, I, O);

        bn_coef<<<(O + 255) / 256, 256, 0, stream>>>(
            flag, gsA, gqA, gsB, gqB, gamma, beta, A, C, B, O, 0);

        bn_apply<<<napply, 256, 0, stream>>>(y, A, C, O, n4o);
    } else {
        float* gsB = wsf + 4;
        float* gqB = gsB + O;
        float* A   = gqB + O;
        float* C   = A + O;

        hipMemsetAsync(d_ws, 0, (4 + 2 * (size_t)O) * sizeof(float), stream);

        kan_forward<<<dim3(O / OT, B / BT), TPB, 0, stream>>>(
            x, scale, bias, weight, flag, 1, y, gsB, gqB, B, I, O);

        bn_coef<<<(O + 255) / 256, 256, 0, stream>>>(
            flag, gsB, gqB, gsB, gqB, gamma, beta, A, C, B, O, 1);

        bn_apply<<<napply, 256, 0, stream>>>(y, A, C, O, n4o);
    }
}